// Round 11
// baseline (286.292 us; speedup 1.0000x reference)
//
#include <hip/hip_runtime.h>
#include <math.h>

#define NP 4096
#define F_IN 64
#define HG 64
#define NC 64
#define NT 32
#define NE 65536
#define HOUT 12
#define LEAKY 0.2f
#define LN_EPS 1e-5f

// ---- DPP reductions ----
template <int CTRL>
__device__ __forceinline__ float dppadd(float v, float x) {   // v + dpp(x); invalid lanes add 0
    int r = __builtin_amdgcn_update_dpp(0, __builtin_bit_cast(int, x), CTRL, 0xF, 0xF, false);
    return v + __builtin_bit_cast(float, r);
}
__device__ __forceinline__ float rowsum16(float v) {   // every lane gets its row-of-16 total
    v = dppadd<0x128>(v, v);   // row_ror:8
    v = dppadd<0x124>(v, v);   // row_ror:4
    v = dppadd<0x122>(v, v);   // row_ror:2
    v = dppadd<0x121>(v, v);   // row_ror:1
    return v;
}
__device__ __forceinline__ float laneXorSum(float v) { // lane-wise cross-row butterfly (16,32)
    v += __shfl_xor(v, 16, 64);
    v += __shfl_xor(v, 32, 64);
    return v;
}
__device__ __forceinline__ int waveSumInt(int v) {
#pragma unroll
    for (int d = 1; d < 64; d <<= 1) v += __shfl_xor(v, d, 64);
    return v;
}

#define FMA4(Acomp, B, r)                                                     \
    acc[r][0] += (Acomp) * (B).x; acc[r][1] += (Acomp) * (B).y;               \
    acc[r][2] += (Acomp) * (B).z; acc[r][3] += (Acomp) * (B).w;

// ---- K0: pre-transpose W_time/W_res + init out with bias ----
__global__ __launch_bounds__(256) void k_prep(const float* __restrict__ W_time,
        const float* __restrict__ W_res, const float* __restrict__ bf,
        float* __restrict__ wtT, float* __restrict__ wrT, float* __restrict__ out) {
    int b = blockIdx.x, tid = threadIdx.x;
    if (b < 16) {
        int i = b * 256 + tid;
        wtT[i] = W_time[(i & 63) * 64 + (i >> 6)];
    } else if (b < 32) {
        int i = (b - 16) * 256 + tid;
        wrT[i] = W_res[(i & 63) * 64 + (i >> 6)];
    } else {
        int i = (b - 32) * 256 + tid;       // 0 .. NP*HOUT-1
        out[i] = bf[i % HOUT];
    }
}

// ---- K1: hl|hr = X[p]^T @ [Wl|Wr]; rs = X[p]^T @ W_res^T + b_res ----
// 2 p per block; B staged in LDS; 52 KB LDS -> 3 blocks/CU
__global__ __launch_bounds__(256) void k_hlhr(const float* __restrict__ X,
        const float* __restrict__ Wl, const float* __restrict__ Wr,
        const float* __restrict__ wrT, const float* __restrict__ b_res,
        float* __restrict__ hl, float* __restrict__ hr, float* __restrict__ rs) {
    __shared__ float xs[2][F_IN][36];
    __shared__ float bk[F_IN][132];
    int p0 = blockIdx.x * 2, tid = threadIdx.x;
    const float4* Xp = (const float4*)(X + (size_t)p0 * F_IN * NT);
    for (int i4 = tid; i4 < 1024; i4 += 256) {
        int pp = i4 >> 9, f = (i4 >> 3) & 63, t0 = (i4 & 7) * 4;
        *(float4*)&xs[pp][f][t0] = Xp[i4];
    }
    const float4* Wl4 = (const float4*)Wl;
    const float4* Wr4 = (const float4*)Wr;
    for (int i4 = tid; i4 < 1024; i4 += 256) {     // f = i4>>4, h4 = (i4&15)*4
        int f = i4 >> 4, h4 = (i4 & 15) * 4;
        *(float4*)&bk[f][h4] = Wl4[i4];
        *(float4*)&bk[f][64 + h4] = Wr4[i4];
    }
    __syncthreads();
    {
        int ng = tid & 31, tg = tid >> 5;
        int n0 = ng * 4, col = (ng & 15) * 4, t0 = tg * 4;
        float acc[8][4];
#pragma unroll
        for (int i = 0; i < 8; ++i)
#pragma unroll
            for (int j = 0; j < 4; ++j) acc[i][j] = 0.f;
#pragma unroll 4
        for (int f = 0; f < F_IN; ++f) {
            float4 B = *(const float4*)&bk[f][n0];
            float4 A0 = *(const float4*)&xs[0][f][t0];
            float4 A1 = *(const float4*)&xs[1][f][t0];
            FMA4(A0.x, B, 0) FMA4(A0.y, B, 1) FMA4(A0.z, B, 2) FMA4(A0.w, B, 3)
            FMA4(A1.x, B, 4) FMA4(A1.y, B, 5) FMA4(A1.z, B, 6) FMA4(A1.w, B, 7)
        }
#pragma unroll
        for (int pp = 0; pp < 2; ++pp) {
#pragma unroll
            for (int i = 0; i < 4; ++i) {
                size_t rb = ((size_t)(t0 + i) * NP + p0 + pp) * HG;
                float4 v;
                v.x = acc[pp * 4 + i][0]; v.y = acc[pp * 4 + i][1];
                v.z = acc[pp * 4 + i][2]; v.w = acc[pp * 4 + i][3];
                if (ng < 16) *(float4*)&hl[rb + col] = v;
                else         *(float4*)&hr[rb + col] = v;
            }
        }
    }
    __syncthreads();
    {
        const float4* wrT4 = (const float4*)wrT;
        for (int i4 = tid; i4 < 1024; i4 += 256) {
            int f = i4 >> 4, c4 = (i4 & 15) * 4;
            *(float4*)&bk[f][c4] = wrT4[i4];
        }
    }
    __syncthreads();
    {
        int cg = tid & 15, tg = tid >> 4;
        int c0 = cg * 4, t0 = tg * 2;
        float4 br4 = *(const float4*)&b_res[c0];
        float acc[4][4];
#pragma unroll
        for (int i = 0; i < 4; ++i) {
            acc[i][0] = br4.x; acc[i][1] = br4.y; acc[i][2] = br4.z; acc[i][3] = br4.w;
        }
#pragma unroll 4
        for (int f = 0; f < F_IN; ++f) {
            float4 B = *(const float4*)&bk[f][c0];
            float2 A0 = *(const float2*)&xs[0][f][t0];
            float2 A1 = *(const float2*)&xs[1][f][t0];
            FMA4(A0.x, B, 0) FMA4(A0.y, B, 1)
            FMA4(A1.x, B, 2) FMA4(A1.y, B, 3)
        }
#pragma unroll
        for (int pp = 0; pp < 2; ++pp) {
#pragma unroll
            for (int i = 0; i < 2; ++i) {
                float4 v;
                v.x = acc[pp * 2 + i][0]; v.y = acc[pp * 2 + i][1];
                v.z = acc[pp * 2 + i][2]; v.w = acc[pp * 2 + i][3];
                *(float4*)&rs[((size_t)(t0 + i) * NP + p0 + pp) * NC + c0] = v;
            }
        }
    }
}

// ---- K2a: per-(t,c,r) counts into cnt2[t][c][d] + per-256-dst segment sums ----
__global__ __launch_bounds__(256) void k_count(const int* __restrict__ EI,
        int* __restrict__ cnt2, int* __restrict__ segsum2) {
    __shared__ int loc[1024];
    int b = blockIdx.x;
    int j = b >> 3;
    int t = (b & 7) + 8 * (j & 3);
    int cr = j >> 2;
    int c = cr & 3, r = cr >> 2;
    int tid = threadIdx.x;
    loc[tid] = 0; loc[tid + 256] = 0; loc[tid + 512] = 0; loc[tid + 768] = 0;
    __syncthreads();
    int base = r << 10;
    const int4* dstA = (const int4*)(EI + (size_t)t * 2 * NE + NE) + c * (NE / 16);
    for (int i = tid; i < NE / 16; i += 256) {
        int4 d = dstA[i];
        if ((d.x >> 10) == r) atomicAdd(&loc[d.x - base], 1);
        if ((d.y >> 10) == r) atomicAdd(&loc[d.y - base], 1);
        if ((d.z >> 10) == r) atomicAdd(&loc[d.z - base], 1);
        if ((d.w >> 10) == r) atomicAdd(&loc[d.w - base], 1);
    }
    __syncthreads();
    int o = (t * 4 + c) * NP + base + tid;
    cnt2[o] = loc[tid];
    cnt2[o + 256] = loc[tid + 256];
    cnt2[o + 512] = loc[tid + 512];
    cnt2[o + 768] = loc[tid + 768];
    int wv = tid >> 6, lane = tid & 63;
    int s = loc[wv * 256 + lane] + loc[wv * 256 + lane + 64]
          + loc[wv * 256 + lane + 128] + loc[wv * 256 + lane + 192];
    s = waveSumInt(s);
    if (lane == 0) segsum2[(t * 4 + c) * 16 + r * 4 + wv] = s;
}

// ---- K2b: scan; block = (t, 256-dst segment); 512 blocks, all coalesced ----
__global__ __launch_bounds__(256) void k_scan(const int* __restrict__ cnt2,
        const int* __restrict__ segsum2, int* __restrict__ cnt,
        int* __restrict__ start, int* __restrict__ start2) {
    __shared__ int sc[256];
    __shared__ int preS;
    int b = blockIdx.x;
    int t = b >> 4, seg = b & 15;
    int tid = threadIdx.x;
    if (tid < 64) {
        int c = tid >> 4, s = tid & 15;
        int v = (s < seg) ? segsum2[(t * 4 + c) * 16 + s] : 0;
        v = waveSumInt(v);
        if (tid == 0) preS = v;
    }
    int d = seg * 256 + tid;
    int q0 = cnt2[(t * 4 + 0) * NP + d];
    int q1 = cnt2[(t * 4 + 1) * NP + d];
    int q2 = cnt2[(t * 4 + 2) * NP + d];
    int q3 = cnt2[(t * 4 + 3) * NP + d];
    int deg = q0 + q1 + q2 + q3;
    sc[tid] = deg;
    __syncthreads();
    int pre = preS;
    for (int dd = 1; dd < 256; dd <<= 1) {
        int v = (tid >= dd) ? sc[tid - dd] : 0;
        __syncthreads();
        sc[tid] += v;
        __syncthreads();
    }
    int exc = sc[tid] - deg;
    int st = t * NE + pre + exc;
    cnt[t * NP + d] = deg;
    start[t * NP + d] = st;
    start2[(t * 4 + 0) * NP + d] = st; st += q0;
    start2[(t * 4 + 1) * NP + d] = st; st += q1;
    start2[(t * 4 + 2) * NP + d] = st; st += q2;
    start2[(t * 4 + 3) * NP + d] = st;
}

// ---- K2c: fill from per-(t,c) cursors; block-local LDS atomics only ----
__global__ __launch_bounds__(256) void k_fill(const int* __restrict__ EI,
        const int* __restrict__ start2, int* __restrict__ ssrc) {
    __shared__ int curs_l[1024];
    int b = blockIdx.x;
    int j = b >> 3;
    int t = (b & 7) + 8 * (j & 3);
    int cr = j >> 2;
    int c = cr & 3, r = cr >> 2;
    int tid = threadIdx.x;
    int base = r << 10;
    int o = (t * 4 + c) * NP + base + tid;
    curs_l[tid] = start2[o];
    curs_l[tid + 256] = start2[o + 256];
    curs_l[tid + 512] = start2[o + 512];
    curs_l[tid + 768] = start2[o + 768];
    __syncthreads();
    const int4* srcA = (const int4*)(EI + (size_t)t * 2 * NE) + c * (NE / 16);
    const int4* dstA = (const int4*)(EI + (size_t)t * 2 * NE + NE) + c * (NE / 16);
    for (int i = tid; i < NE / 16; i += 256) {
        int4 s = srcA[i];
        int4 d = dstA[i];
        if ((d.x >> 10) == r) { int sl = atomicAdd(&curs_l[d.x - base], 1); ssrc[sl] = s.x; }
        if ((d.y >> 10) == r) { int sl = atomicAdd(&curs_l[d.y - base], 1); ssrc[sl] = s.y; }
        if ((d.z >> 10) == r) { int sl = atomicAdd(&curs_l[d.z - base], 1); ssrc[sl] = s.z; }
        if ((d.w >> 10) == r) { int sl = atomicAdd(&curs_l[d.w - base], 1); ssrc[sl] = s.w; }
    }
}

// ---- K3: GATv2; wave per dst; 8 edges/iter (2 independent 4-edge chains) ----
__global__ __launch_bounds__(256) void k_gat(const float* __restrict__ hl,
        float* __restrict__ hr,
        const int* __restrict__ start, const int* __restrict__ cnt,
        const int* __restrict__ ssrc,
        const float* __restrict__ att, const float* __restrict__ gat_b) {
    __shared__ int sidx[4][64];
    int b = blockIdx.x;              // 32768 blocks
    int k = b >> 3;                  // 0..4095
    int t = (b & 7) + 8 * (k >> 10); // one t per XCD at a time
    int ws = threadIdx.x >> 6;
    int i = (k & 1023) * 4 + ws;
    int lane = threadIdx.x & 63;
    int row = lane >> 4;
    int c0 = (lane & 15) * 4;
    size_t nbase = ((size_t)t * NP + i) * HG;
    const float* hlt = hl + (size_t)t * NP * HG;
    float4 r4 = *(const float4*)&hr[nbase + c0];
    float4 at4 = *(const float4*)&att[c0];
    int s0 = start[t * NP + i];
    int deg = cnt[t * NP + i];
    float l = 0.f;
    float4 acc = {0.f, 0.f, 0.f, 0.f};
    for (int base = 0; base < deg; base += 64) {
        int chunk = deg - base;
        chunk = (chunk < 64) ? chunk : 64;
        int stage = (lane < chunk) ? lane : 0;
        sidx[ws][lane] = ssrc[s0 + base + stage];
        int nfull = chunk & ~7;
        int j = 0;
        for (; j < nfull; j += 8) {
            int src0 = sidx[ws][j + row];
            int src1 = sidx[ws][j + 4 + row];
            float4 h0 = *(const float4*)&hlt[((size_t)src0 << 6) + c0];
            float4 h1 = *(const float4*)&hlt[((size_t)src1 << 6) + c0];
            float4 z0, z1;
            z0.x = h0.x + r4.x; z0.y = h0.y + r4.y; z0.z = h0.z + r4.z; z0.w = h0.w + r4.w;
            z1.x = h1.x + r4.x; z1.y = h1.y + r4.y; z1.z = h1.z + r4.z; z1.w = h1.w + r4.w;
            z0.x = fmaxf(z0.x, LEAKY * z0.x); z0.y = fmaxf(z0.y, LEAKY * z0.y);
            z0.z = fmaxf(z0.z, LEAKY * z0.z); z0.w = fmaxf(z0.w, LEAKY * z0.w);
            z1.x = fmaxf(z1.x, LEAKY * z1.x); z1.y = fmaxf(z1.y, LEAKY * z1.y);
            z1.z = fmaxf(z1.z, LEAKY * z1.z); z1.w = fmaxf(z1.w, LEAKY * z1.w);
            float e0 = rowsum16(z0.x * at4.x + z0.y * at4.y + z0.z * at4.z + z0.w * at4.w);
            float e1 = rowsum16(z1.x * at4.x + z1.y * at4.y + z1.z * at4.z + z1.w * at4.w);
            float w0 = __expf(e0);
            float w1 = __expf(e1);
            l += w0 + w1;
            acc.x += w0 * h0.x + w1 * h1.x;
            acc.y += w0 * h0.y + w1 * h1.y;
            acc.z += w0 * h0.z + w1 * h1.z;
            acc.w += w0 * h0.w + w1 * h1.w;
        }
        for (; j < chunk; j += 4) {
            int jj = j + row;
            int src = sidx[ws][(jj < chunk) ? jj : 0];
            float4 ha = *(const float4*)&hlt[((size_t)src << 6) + c0];
            float4 za;
            za.x = ha.x + r4.x; za.y = ha.y + r4.y; za.z = ha.z + r4.z; za.w = ha.w + r4.w;
            za.x = fmaxf(za.x, LEAKY * za.x);
            za.y = fmaxf(za.y, LEAKY * za.y);
            za.z = fmaxf(za.z, LEAKY * za.z);
            za.w = fmaxf(za.w, LEAKY * za.w);
            float ep = za.x * at4.x + za.y * at4.y + za.z * at4.z + za.w * at4.w;
            float e = rowsum16(ep);
            float w = __expf(e);
            w = (jj < chunk) ? w : 0.f;
            l += w;
            acc.x += w * ha.x; acc.y += w * ha.y; acc.z += w * ha.z; acc.w += w * ha.w;
        }
    }
    float lt = laneXorSum(l);
    acc.x = laneXorSum(acc.x);
    acc.y = laneXorSum(acc.y);
    acc.z = laneXorSum(acc.z);
    acc.w = laneXorSum(acc.w);
    if (row == 0) {
        float inv = (deg > 0) ? (1.0f / lt) : 0.f;
        float4 gb = *(const float4*)&gat_b[c0];
        float4 o;
        o.x = fmaxf(acc.x * inv + gb.x, 0.f);
        o.y = fmaxf(acc.y * inv + gb.y, 0.f);
        o.z = fmaxf(acc.z * inv + gb.z, 0.f);
        o.w = fmaxf(acc.w * inv + gb.w, 0.f);
        *(float4*)&hr[nbase + c0] = o;
    }
}

// ---- K4 (fused post+final): per (64-p tile, 4 stride-8 t's):
//      X_hat @ wtT + b_time + rs, ReLU, LN, then contract with Wf into out (atomicAdd) ----
__global__ __launch_bounds__(256) void k_pf(const float* __restrict__ Xhat,
        const float* __restrict__ wtT, const float* __restrict__ b_time,
        const float* __restrict__ rs, const float* __restrict__ ln_g,
        const float* __restrict__ ln_b, const float* __restrict__ Wf,
        float* __restrict__ out) {
    __shared__ float in_t[64][68];
    __shared__ float bk[64][68];
    int bx = blockIdx.x;             // 512 = 64 ptiles x 8 tchunks; tc = bx&7 -> t ≡ tc (mod 8) = XCD match
    int tc = bx & 7;
    int p0 = (bx >> 3) * 64;
    int tid = threadIdx.x;
    const float4* wsrc = (const float4*)wtT;
    for (int i4 = tid; i4 < 1024; i4 += 256) {
        int h = i4 >> 4, c4 = (i4 & 15) * 4;
        *(float4*)&bk[h][c4] = wsrc[i4];
    }
    int cg = tid & 15, pg = tid >> 4;
    int c0 = cg * 4, pl = pg * 4;
    float4 bt4 = *(const float4*)&b_time[c0];
    float4 lg = *(const float4*)&ln_g[c0];
    float4 lb = *(const float4*)&ln_b[c0];
    float ot[4][HOUT];
#pragma unroll
    for (int i = 0; i < 4; ++i)
#pragma unroll
        for (int o = 0; o < HOUT; ++o) ot[i][o] = 0.f;
    for (int ti = 0; ti < 4; ++ti) {
        int t = tc + ti * 8;
        __syncthreads();   // protect in_t from previous iteration's readers
        const float4* src = (const float4*)(Xhat + ((size_t)t * NP + p0) * HG);
        for (int i4 = tid; i4 < 1024; i4 += 256) {
            int pp = i4 >> 4, c4 = (i4 & 15) * 4;
            *(float4*)&in_t[pp][c4] = src[i4];
        }
        __syncthreads();
        float acc[4][4];
#pragma unroll
        for (int i = 0; i < 4; ++i) {
            acc[i][0] = bt4.x; acc[i][1] = bt4.y; acc[i][2] = bt4.z; acc[i][3] = bt4.w;
        }
#pragma unroll
        for (int k4 = 0; k4 < 16; ++k4) {
            float4 A0 = *(const float4*)&in_t[pl + 0][k4 * 4];
            float4 A1 = *(const float4*)&in_t[pl + 1][k4 * 4];
            float4 A2 = *(const float4*)&in_t[pl + 2][k4 * 4];
            float4 A3 = *(const float4*)&in_t[pl + 3][k4 * 4];
            float4 B0 = *(const float4*)&bk[k4 * 4 + 0][c0];
            FMA4(A0.x, B0, 0) FMA4(A1.x, B0, 1) FMA4(A2.x, B0, 2) FMA4(A3.x, B0, 3)
            float4 B1 = *(const float4*)&bk[k4 * 4 + 1][c0];
            FMA4(A0.y, B1, 0) FMA4(A1.y, B1, 1) FMA4(A2.y, B1, 2) FMA4(A3.y, B1, 3)
            float4 B2 = *(const float4*)&bk[k4 * 4 + 2][c0];
            FMA4(A0.z, B2, 0) FMA4(A1.z, B2, 1) FMA4(A2.z, B2, 2) FMA4(A3.z, B2, 3)
            float4 B3 = *(const float4*)&bk[k4 * 4 + 3][c0];
            FMA4(A0.w, B3, 0) FMA4(A1.w, B3, 1) FMA4(A2.w, B3, 2) FMA4(A3.w, B3, 3)
        }
        float4 ynv[4];
#pragma unroll
        for (int i = 0; i < 4; ++i) {
            size_t prow = (size_t)t * NP + p0 + pl + i;
            float4 r4 = *(const float4*)&rs[prow * NC + c0];
            float y0 = fmaxf(acc[i][0] + r4.x, 0.f), y1 = fmaxf(acc[i][1] + r4.y, 0.f);
            float y2 = fmaxf(acc[i][2] + r4.z, 0.f), y3 = fmaxf(acc[i][3] + r4.w, 0.f);
            float s = rowsum16(y0 + y1 + y2 + y3);
            float ss = rowsum16(y0 * y0 + y1 * y1 + y2 * y2 + y3 * y3);
            float mu = s * (1.f / 64.f);
            float var = ss * (1.f / 64.f) - mu * mu;
            float rsd = rsqrtf(var + LN_EPS);
            ynv[i].x = (y0 - mu) * rsd * lg.x + lb.x;
            ynv[i].y = (y1 - mu) * rsd * lg.y + lb.y;
            ynv[i].z = (y2 - mu) * rsd * lg.z + lb.z;
            ynv[i].w = (y3 - mu) * rsd * lg.w + lb.w;
        }
#pragma unroll
        for (int o = 0; o < HOUT; ++o) {
            float4 w4 = *(const float4*)&Wf[(size_t)o * NT * NC + t * NC + c0];
#pragma unroll
            for (int i = 0; i < 4; ++i)
                ot[i][o] += ynv[i].x * w4.x + ynv[i].y * w4.y
                          + ynv[i].z * w4.z + ynv[i].w * w4.w;
        }
    }
    // reduce partials across the 16 c-groups (row of 16 lanes), then one atomic per (p,o)
#pragma unroll
    for (int i = 0; i < 4; ++i)
#pragma unroll
        for (int o = 0; o < HOUT; ++o) ot[i][o] = rowsum16(ot[i][o]);
    if (cg == 0) {
#pragma unroll
        for (int i = 0; i < 4; ++i) {
            int p = p0 + pl + i;
#pragma unroll
            for (int o = 0; o < HOUT; ++o)
                atomicAdd(&out[p * HOUT + o], ot[i][o]);
        }
    }
}

extern "C" void kernel_launch(void* const* d_in, const int* in_sizes, int n_in,
                              void* d_out, int out_size, void* d_ws, size_t ws_size,
                              hipStream_t stream) {
    const float* X      = (const float*)d_in[0];
    const int*   EI     = (const int*)d_in[1];
    const float* Wl     = (const float*)d_in[2];
    const float* Wr     = (const float*)d_in[3];
    const float* att    = (const float*)d_in[4];
    const float* gat_b  = (const float*)d_in[5];
    const float* W_time = (const float*)d_in[6];
    const float* b_time = (const float*)d_in[7];
    const float* W_res  = (const float*)d_in[8];
    const float* b_res  = (const float*)d_in[9];
    const float* ln_g   = (const float*)d_in[10];
    const float* ln_b   = (const float*)d_in[11];
    const float* Wf     = (const float*)d_in[12];
    const float* bf     = (const float*)d_in[13];
    float* out = (float*)d_out;

    char* ws = (char*)d_ws;
    const size_t MB = 1024 * 1024;
    float* hl    = (float*)(ws);                    // 32 MB
    float* hr    = (float*)(ws + 32 * MB);          // 32 MB (becomes X_hat)
    float* rs    = (float*)(ws + 64 * MB);          // 32 MB residual
    int*   ssrc  = (int*)  (ws + 96 * MB);          // 8 MB
    int*   cnt   = (int*)  (ws + 104 * MB);         // 512 KB
    int*   strt  = (int*)  (ws + 104 * MB + 512 * 1024);
    float* wtT   = (float*)(ws + 105 * MB);         // 16 KB
    float* wrT   = (float*)(ws + 105 * MB + 16384);
    int*   segs2 = (int*)  (ws + 105 * MB + 32768); // 8 KB [t][c][16]
    int*   cnt2  = (int*)  (ws + 106 * MB);         // 2 MB  [t][4][NP]
    int*   strt2 = (int*)  (ws + 108 * MB);         // 2 MB  [t][4][NP]

    k_prep <<<224, 256, 0, stream>>>(W_time, W_res, bf, wtT, wrT, out);
    k_hlhr <<<NP / 2, 256, 0, stream>>>(X, Wl, Wr, wrT, b_res, hl, hr, rs);
    k_count<<<512, 256, 0, stream>>>(EI, cnt2, segs2);
    k_scan <<<NT * 16, 256, 0, stream>>>(cnt2, segs2, cnt, strt, strt2);
    k_fill <<<512, 256, 0, stream>>>(EI, strt2, ssrc);
    k_gat  <<<(NT * NP) / 4, 256, 0, stream>>>(hl, hr, strt, cnt, ssrc, att, gat_b);
    k_pf   <<<512, 256, 0, stream>>>(hr, wtT, b_time, rs, ln_g, ln_b, Wf, out);
}

// Round 12
// 279.043 us; speedup vs baseline: 1.0260x; 1.0260x over previous
//
#include <hip/hip_runtime.h>
#include <math.h>

#define NP 4096
#define F_IN 64
#define HG 64
#define NC 64
#define NT 32
#define NE 65536
#define HOUT 12
#define LEAKY 0.2f
#define LN_EPS 1e-5f

// ---- DPP reductions ----
template <int CTRL>
__device__ __forceinline__ float dppadd(float v, float x) {   // v + dpp(x); invalid lanes add 0
    int r = __builtin_amdgcn_update_dpp(0, __builtin_bit_cast(int, x), CTRL, 0xF, 0xF, false);
    return v + __builtin_bit_cast(float, r);
}
__device__ __forceinline__ float rowsum16(float v) {   // every lane gets its row-of-16 total
    v = dppadd<0x128>(v, v);   // row_ror:8
    v = dppadd<0x124>(v, v);   // row_ror:4
    v = dppadd<0x122>(v, v);   // row_ror:2
    v = dppadd<0x121>(v, v);   // row_ror:1
    return v;
}
__device__ __forceinline__ float laneXorSum(float v) { // lane-wise cross-row butterfly (16,32)
    v += __shfl_xor(v, 16, 64);
    v += __shfl_xor(v, 32, 64);
    return v;
}
__device__ __forceinline__ int waveSumInt(int v) {
#pragma unroll
    for (int d = 1; d < 64; d <<= 1) v += __shfl_xor(v, d, 64);
    return v;
}

#define FMA4(Acomp, B, r)                                                     \
    acc[r][0] += (Acomp) * (B).x; acc[r][1] += (Acomp) * (B).y;               \
    acc[r][2] += (Acomp) * (B).z; acc[r][3] += (Acomp) * (B).w;

// ============ K_FRONT: one launch, three independent roles ============
// blocks [0,1024):     CSR count (t, chunk c of NE/8, range r of 1024 dsts)
// blocks [1024,3072):  hlhr GEMM (2 p per block)
// blocks [3072,3088):  W_time transpose -> wtT
// blocks [3088,3280):  out init with bias
__global__ __launch_bounds__(256) void k_front(const float* __restrict__ X,
        const float* __restrict__ Wl, const float* __restrict__ Wr,
        const float* __restrict__ W_res, const float* __restrict__ b_res,
        const float* __restrict__ W_time, const float* __restrict__ bf,
        const int* __restrict__ EI,
        float* __restrict__ hl, float* __restrict__ hr, float* __restrict__ rs,
        float* __restrict__ wtT, float* __restrict__ out,
        int* __restrict__ cnt2, int* __restrict__ segsum2) {
    __shared__ float smem[13312];   // 52 KB, shared across roles
    int b = blockIdx.x;
    int tid = threadIdx.x;
    if (b < 1024) {
        // ---- count ----
        int* loc = (int*)smem;      // [1024]
        int j = b >> 3;
        int t = (b & 7) + 8 * (j & 3);   // t pinned to XCD
        int cr = j >> 2;
        int c = cr & 7, r = cr >> 3;
        loc[tid] = 0; loc[tid + 256] = 0; loc[tid + 512] = 0; loc[tid + 768] = 0;
        __syncthreads();
        int base = r << 10;
        const int4* dstA = (const int4*)(EI + (size_t)t * 2 * NE + NE) + c * (NE / 32);
        for (int i = tid; i < NE / 32; i += 256) {
            int4 d = dstA[i];
            if ((d.x >> 10) == r) atomicAdd(&loc[d.x - base], 1);
            if ((d.y >> 10) == r) atomicAdd(&loc[d.y - base], 1);
            if ((d.z >> 10) == r) atomicAdd(&loc[d.z - base], 1);
            if ((d.w >> 10) == r) atomicAdd(&loc[d.w - base], 1);
        }
        __syncthreads();
        int o = (t * 8 + c) * NP + base + tid;
        cnt2[o] = loc[tid];
        cnt2[o + 256] = loc[tid + 256];
        cnt2[o + 512] = loc[tid + 512];
        cnt2[o + 768] = loc[tid + 768];
        int wv = tid >> 6, lane = tid & 63;
        int s = loc[wv * 256 + lane] + loc[wv * 256 + lane + 64]
              + loc[wv * 256 + lane + 128] + loc[wv * 256 + lane + 192];
        s = waveSumInt(s);
        if (lane == 0) segsum2[(t * 8 + c) * 16 + r * 4 + wv] = s;
    } else if (b < 3072) {
        // ---- hlhr: hl|hr = X^T @ [Wl|Wr]; rs = X^T @ W_res^T + b_res ----
        float (*xs)[F_IN][36] = (float (*)[F_IN][36])smem;          // 2*64*36
        float (*bk)[132] = (float (*)[132])(smem + 4608);           // 64*132
        int p0 = (b - 1024) * 2;
        const float4* Xp = (const float4*)(X + (size_t)p0 * F_IN * NT);
        for (int i4 = tid; i4 < 1024; i4 += 256) {
            int pp = i4 >> 9, f = (i4 >> 3) & 63, t0 = (i4 & 7) * 4;
            *(float4*)&xs[pp][f][t0] = Xp[i4];
        }
        const float4* Wl4 = (const float4*)Wl;
        const float4* Wr4 = (const float4*)Wr;
        for (int i4 = tid; i4 < 1024; i4 += 256) {
            int f = i4 >> 4, h4 = (i4 & 15) * 4;
            *(float4*)&bk[f][h4] = Wl4[i4];
            *(float4*)&bk[f][64 + h4] = Wr4[i4];
        }
        __syncthreads();
        {
            int ng = tid & 31, tg = tid >> 5;
            int n0 = ng * 4, col = (ng & 15) * 4, t0 = tg * 4;
            float acc[8][4];
#pragma unroll
            for (int i = 0; i < 8; ++i)
#pragma unroll
                for (int j2 = 0; j2 < 4; ++j2) acc[i][j2] = 0.f;
#pragma unroll 4
            for (int f = 0; f < F_IN; ++f) {
                float4 B = *(const float4*)&bk[f][n0];
                float4 A0 = *(const float4*)&xs[0][f][t0];
                float4 A1 = *(const float4*)&xs[1][f][t0];
                FMA4(A0.x, B, 0) FMA4(A0.y, B, 1) FMA4(A0.z, B, 2) FMA4(A0.w, B, 3)
                FMA4(A1.x, B, 4) FMA4(A1.y, B, 5) FMA4(A1.z, B, 6) FMA4(A1.w, B, 7)
            }
#pragma unroll
            for (int pp = 0; pp < 2; ++pp) {
#pragma unroll
                for (int i = 0; i < 4; ++i) {
                    size_t rb = ((size_t)(t0 + i) * NP + p0 + pp) * HG;
                    float4 v;
                    v.x = acc[pp * 4 + i][0]; v.y = acc[pp * 4 + i][1];
                    v.z = acc[pp * 4 + i][2]; v.w = acc[pp * 4 + i][3];
                    if (ng < 16) *(float4*)&hl[rb + col] = v;
                    else         *(float4*)&hr[rb + col] = v;
                }
            }
        }
        __syncthreads();
        for (int i = tid; i < F_IN * NC; i += 256) {
            int c = i >> 6, f = i & 63;       // W_res[c][f] coalesced read
            bk[f][c] = W_res[i];              // transposed LDS write (8-way, once)
        }
        __syncthreads();
        {
            int cg = tid & 15, tg = tid >> 4;
            int c0 = cg * 4, t0 = tg * 2;
            float4 br4 = *(const float4*)&b_res[c0];
            float acc[4][4];
#pragma unroll
            for (int i = 0; i < 4; ++i) {
                acc[i][0] = br4.x; acc[i][1] = br4.y; acc[i][2] = br4.z; acc[i][3] = br4.w;
            }
#pragma unroll 4
            for (int f = 0; f < F_IN; ++f) {
                float4 B = *(const float4*)&bk[f][c0];
                float2 A0 = *(const float2*)&xs[0][f][t0];
                float2 A1 = *(const float2*)&xs[1][f][t0];
                FMA4(A0.x, B, 0) FMA4(A0.y, B, 1)
                FMA4(A1.x, B, 2) FMA4(A1.y, B, 3)
            }
#pragma unroll
            for (int pp = 0; pp < 2; ++pp) {
#pragma unroll
                for (int i = 0; i < 2; ++i) {
                    float4 v;
                    v.x = acc[pp * 2 + i][0]; v.y = acc[pp * 2 + i][1];
                    v.z = acc[pp * 2 + i][2]; v.w = acc[pp * 2 + i][3];
                    *(float4*)&rs[((size_t)(t0 + i) * NP + p0 + pp) * NC + c0] = v;
                }
            }
        }
    } else if (b < 3088) {
        int i = (b - 3072) * 256 + tid;
        wtT[i] = W_time[(i & 63) * 64 + (i >> 6)];
    } else {
        int i = (b - 3088) * 256 + tid;       // 0 .. NP*HOUT-1
        out[i] = bf[i % HOUT];
    }
}

// ---- K2b: scan; block = (t, 256-dst segment); start2 written in-place over cnt2 ----
__global__ __launch_bounds__(256) void k_scan(int* __restrict__ cnt2,
        const int* __restrict__ segsum2, int* __restrict__ cnt,
        int* __restrict__ start) {
    __shared__ int sc[256];
    __shared__ int preS;
    int b = blockIdx.x;
    int t = b >> 4, seg = b & 15;
    int tid = threadIdx.x;
    if (tid < 64) {                           // one wave: prefix of earlier segments over 8 chunks
        int s = tid & 15, cp = tid >> 4;      // cp in [0,4): chunk pair
        int v = 0;
        if (s < seg) {
            v = segsum2[(t * 8 + cp * 2 + 0) * 16 + s]
              + segsum2[(t * 8 + cp * 2 + 1) * 16 + s];
        }
        v = waveSumInt(v);
        if (tid == 0) preS = v;
    }
    int d = seg * 256 + tid;
    int q[8];
    int deg = 0;
#pragma unroll
    for (int c = 0; c < 8; ++c) {
        q[c] = cnt2[(t * 8 + c) * NP + d];
        deg += q[c];
    }
    sc[tid] = deg;
    __syncthreads();
    int pre = preS;
    for (int dd = 1; dd < 256; dd <<= 1) {
        int v = (tid >= dd) ? sc[tid - dd] : 0;
        __syncthreads();
        sc[tid] += v;
        __syncthreads();
    }
    int exc = sc[tid] - deg;
    int st = t * NE + pre + exc;
    cnt[t * NP + d] = deg;
    start[t * NP + d] = st;
#pragma unroll
    for (int c = 0; c < 8; ++c) {
        int qq = q[c];
        cnt2[(t * 8 + c) * NP + d] = st;      // becomes start2
        st += qq;
    }
}

// ---- K2c: fill; block = (t, chunk c of NE/8, range r); LDS cursors ----
__global__ __launch_bounds__(256) void k_fill(const int* __restrict__ EI,
        const int* __restrict__ start2, int* __restrict__ ssrc) {
    __shared__ int curs_l[1024];
    int b = blockIdx.x;
    int j = b >> 3;
    int t = (b & 7) + 8 * (j & 3);
    int cr = j >> 2;
    int c = cr & 7, r = cr >> 3;
    int tid = threadIdx.x;
    int base = r << 10;
    int o = (t * 8 + c) * NP + base + tid;
    curs_l[tid] = start2[o];
    curs_l[tid + 256] = start2[o + 256];
    curs_l[tid + 512] = start2[o + 512];
    curs_l[tid + 768] = start2[o + 768];
    __syncthreads();
    const int4* srcA = (const int4*)(EI + (size_t)t * 2 * NE) + c * (NE / 32);
    const int4* dstA = (const int4*)(EI + (size_t)t * 2 * NE + NE) + c * (NE / 32);
    for (int i = tid; i < NE / 32; i += 256) {
        int4 s = srcA[i];
        int4 d = dstA[i];
        if ((d.x >> 10) == r) { int sl = atomicAdd(&curs_l[d.x - base], 1); ssrc[sl] = s.x; }
        if ((d.y >> 10) == r) { int sl = atomicAdd(&curs_l[d.y - base], 1); ssrc[sl] = s.y; }
        if ((d.z >> 10) == r) { int sl = atomicAdd(&curs_l[d.z - base], 1); ssrc[sl] = s.z; }
        if ((d.w >> 10) == r) { int sl = atomicAdd(&curs_l[d.w - base], 1); ssrc[sl] = s.w; }
    }
}

// ---- K3: GATv2; wave per dst; 8 edges/iter (2 independent 4-edge chains) ----
__global__ __launch_bounds__(256) void k_gat(const float* __restrict__ hl,
        float* __restrict__ hr,
        const int* __restrict__ start, const int* __restrict__ cnt,
        const int* __restrict__ ssrc,
        const float* __restrict__ att, const float* __restrict__ gat_b) {
    __shared__ int sidx[4][64];
    int b = blockIdx.x;              // 32768 blocks
    int k = b >> 3;                  // 0..4095
    int t = (b & 7) + 8 * (k >> 10); // one t per XCD at a time
    int ws = threadIdx.x >> 6;
    int i = (k & 1023) * 4 + ws;
    int lane = threadIdx.x & 63;
    int row = lane >> 4;
    int c0 = (lane & 15) * 4;
    size_t nbase = ((size_t)t * NP + i) * HG;
    const float* hlt = hl + (size_t)t * NP * HG;
    float4 r4 = *(const float4*)&hr[nbase + c0];
    float4 at4 = *(const float4*)&att[c0];
    int s0 = start[t * NP + i];
    int deg = cnt[t * NP + i];
    float l = 0.f;
    float4 acc = {0.f, 0.f, 0.f, 0.f};
    for (int base = 0; base < deg; base += 64) {
        int chunk = deg - base;
        chunk = (chunk < 64) ? chunk : 64;
        int stage = (lane < chunk) ? lane : 0;
        sidx[ws][lane] = ssrc[s0 + base + stage];
        int nfull = chunk & ~7;
        int j = 0;
        for (; j < nfull; j += 8) {
            int src0 = sidx[ws][j + row];
            int src1 = sidx[ws][j + 4 + row];
            float4 h0 = *(const float4*)&hlt[((size_t)src0 << 6) + c0];
            float4 h1 = *(const float4*)&hlt[((size_t)src1 << 6) + c0];
            float4 z0, z1;
            z0.x = h0.x + r4.x; z0.y = h0.y + r4.y; z0.z = h0.z + r4.z; z0.w = h0.w + r4.w;
            z1.x = h1.x + r4.x; z1.y = h1.y + r4.y; z1.z = h1.z + r4.z; z1.w = h1.w + r4.w;
            z0.x = fmaxf(z0.x, LEAKY * z0.x); z0.y = fmaxf(z0.y, LEAKY * z0.y);
            z0.z = fmaxf(z0.z, LEAKY * z0.z); z0.w = fmaxf(z0.w, LEAKY * z0.w);
            z1.x = fmaxf(z1.x, LEAKY * z1.x); z1.y = fmaxf(z1.y, LEAKY * z1.y);
            z1.z = fmaxf(z1.z, LEAKY * z1.z); z1.w = fmaxf(z1.w, LEAKY * z1.w);
            float e0 = rowsum16(z0.x * at4.x + z0.y * at4.y + z0.z * at4.z + z0.w * at4.w);
            float e1 = rowsum16(z1.x * at4.x + z1.y * at4.y + z1.z * at4.z + z1.w * at4.w);
            float w0 = __expf(e0);
            float w1 = __expf(e1);
            l += w0 + w1;
            acc.x += w0 * h0.x + w1 * h1.x;
            acc.y += w0 * h0.y + w1 * h1.y;
            acc.z += w0 * h0.z + w1 * h1.z;
            acc.w += w0 * h0.w + w1 * h1.w;
        }
        for (; j < chunk; j += 4) {
            int jj = j + row;
            int src = sidx[ws][(jj < chunk) ? jj : 0];
            float4 ha = *(const float4*)&hlt[((size_t)src << 6) + c0];
            float4 za;
            za.x = ha.x + r4.x; za.y = ha.y + r4.y; za.z = ha.z + r4.z; za.w = ha.w + r4.w;
            za.x = fmaxf(za.x, LEAKY * za.x);
            za.y = fmaxf(za.y, LEAKY * za.y);
            za.z = fmaxf(za.z, LEAKY * za.z);
            za.w = fmaxf(za.w, LEAKY * za.w);
            float ep = za.x * at4.x + za.y * at4.y + za.z * at4.z + za.w * at4.w;
            float e = rowsum16(ep);
            float w = __expf(e);
            w = (jj < chunk) ? w : 0.f;
            l += w;
            acc.x += w * ha.x; acc.y += w * ha.y; acc.z += w * ha.z; acc.w += w * ha.w;
        }
    }
    float lt = laneXorSum(l);
    acc.x = laneXorSum(acc.x);
    acc.y = laneXorSum(acc.y);
    acc.z = laneXorSum(acc.z);
    acc.w = laneXorSum(acc.w);
    if (row == 0) {
        float inv = (deg > 0) ? (1.0f / lt) : 0.f;
        float4 gb = *(const float4*)&gat_b[c0];
        float4 o;
        o.x = fmaxf(acc.x * inv + gb.x, 0.f);
        o.y = fmaxf(acc.y * inv + gb.y, 0.f);
        o.z = fmaxf(acc.z * inv + gb.z, 0.f);
        o.w = fmaxf(acc.w * inv + gb.w, 0.f);
        *(float4*)&hr[nbase + c0] = o;
    }
}

// ---- K4 (fused post+final): per (64-p tile, 4 stride-8 t's) ----
__global__ __launch_bounds__(256) void k_pf(const float* __restrict__ Xhat,
        const float* __restrict__ wtT, const float* __restrict__ b_time,
        const float* __restrict__ rs, const float* __restrict__ ln_g,
        const float* __restrict__ ln_b, const float* __restrict__ Wf,
        float* __restrict__ out) {
    __shared__ float in_t[64][68];
    __shared__ float bk[64][68];
    int bx = blockIdx.x;             // 512 = 64 ptiles x 8 tchunks
    int tc = bx & 7;
    int p0 = (bx >> 3) * 64;
    int tid = threadIdx.x;
    const float4* wsrc = (const float4*)wtT;
    for (int i4 = tid; i4 < 1024; i4 += 256) {
        int h = i4 >> 4, c4 = (i4 & 15) * 4;
        *(float4*)&bk[h][c4] = wsrc[i4];
    }
    int cg = tid & 15, pg = tid >> 4;
    int c0 = cg * 4, pl = pg * 4;
    float4 bt4 = *(const float4*)&b_time[c0];
    float4 lg = *(const float4*)&ln_g[c0];
    float4 lb = *(const float4*)&ln_b[c0];
    float ot[4][HOUT];
#pragma unroll
    for (int i = 0; i < 4; ++i)
#pragma unroll
        for (int o = 0; o < HOUT; ++o) ot[i][o] = 0.f;
    for (int ti = 0; ti < 4; ++ti) {
        int t = tc + ti * 8;
        __syncthreads();
        const float4* src = (const float4*)(Xhat + ((size_t)t * NP + p0) * HG);
        for (int i4 = tid; i4 < 1024; i4 += 256) {
            int pp = i4 >> 4, c4 = (i4 & 15) * 4;
            *(float4*)&in_t[pp][c4] = src[i4];
        }
        __syncthreads();
        float acc[4][4];
#pragma unroll
        for (int i = 0; i < 4; ++i) {
            acc[i][0] = bt4.x; acc[i][1] = bt4.y; acc[i][2] = bt4.z; acc[i][3] = bt4.w;
        }
#pragma unroll
        for (int k4 = 0; k4 < 16; ++k4) {
            float4 A0 = *(const float4*)&in_t[pl + 0][k4 * 4];
            float4 A1 = *(const float4*)&in_t[pl + 1][k4 * 4];
            float4 A2 = *(const float4*)&in_t[pl + 2][k4 * 4];
            float4 A3 = *(const float4*)&in_t[pl + 3][k4 * 4];
            float4 B0 = *(const float4*)&bk[k4 * 4 + 0][c0];
            FMA4(A0.x, B0, 0) FMA4(A1.x, B0, 1) FMA4(A2.x, B0, 2) FMA4(A3.x, B0, 3)
            float4 B1 = *(const float4*)&bk[k4 * 4 + 1][c0];
            FMA4(A0.y, B1, 0) FMA4(A1.y, B1, 1) FMA4(A2.y, B1, 2) FMA4(A3.y, B1, 3)
            float4 B2 = *(const float4*)&bk[k4 * 4 + 2][c0];
            FMA4(A0.z, B2, 0) FMA4(A1.z, B2, 1) FMA4(A2.z, B2, 2) FMA4(A3.z, B2, 3)
            float4 B3 = *(const float4*)&bk[k4 * 4 + 3][c0];
            FMA4(A0.w, B3, 0) FMA4(A1.w, B3, 1) FMA4(A2.w, B3, 2) FMA4(A3.w, B3, 3)
        }
        float4 ynv[4];
#pragma unroll
        for (int i = 0; i < 4; ++i) {
            size_t prow = (size_t)t * NP + p0 + pl + i;
            float4 r4 = *(const float4*)&rs[prow * NC + c0];
            float y0 = fmaxf(acc[i][0] + r4.x, 0.f), y1 = fmaxf(acc[i][1] + r4.y, 0.f);
            float y2 = fmaxf(acc[i][2] + r4.z, 0.f), y3 = fmaxf(acc[i][3] + r4.w, 0.f);
            float s = rowsum16(y0 + y1 + y2 + y3);
            float ss = rowsum16(y0 * y0 + y1 * y1 + y2 * y2 + y3 * y3);
            float mu = s * (1.f / 64.f);
            float var = ss * (1.f / 64.f) - mu * mu;
            float rsd = rsqrtf(var + LN_EPS);
            ynv[i].x = (y0 - mu) * rsd * lg.x + lb.x;
            ynv[i].y = (y1 - mu) * rsd * lg.y + lb.y;
            ynv[i].z = (y2 - mu) * rsd * lg.z + lb.z;
            ynv[i].w = (y3 - mu) * rsd * lg.w + lb.w;
        }
#pragma unroll
        for (int o = 0; o < HOUT; ++o) {
            float4 w4 = *(const float4*)&Wf[(size_t)o * NT * NC + t * NC + c0];
#pragma unroll
            for (int i = 0; i < 4; ++i)
                ot[i][o] += ynv[i].x * w4.x + ynv[i].y * w4.y
                          + ynv[i].z * w4.z + ynv[i].w * w4.w;
        }
    }
#pragma unroll
    for (int i = 0; i < 4; ++i)
#pragma unroll
        for (int o = 0; o < HOUT; ++o) ot[i][o] = rowsum16(ot[i][o]);
    if (cg == 0) {
#pragma unroll
        for (int i = 0; i < 4; ++i) {
            int p = p0 + pl + i;
#pragma unroll
            for (int o = 0; o < HOUT; ++o)
                atomicAdd(&out[p * HOUT + o], ot[i][o]);
        }
    }
}

extern "C" void kernel_launch(void* const* d_in, const int* in_sizes, int n_in,
                              void* d_out, int out_size, void* d_ws, size_t ws_size,
                              hipStream_t stream) {
    const float* X      = (const float*)d_in[0];
    const int*   EI     = (const int*)d_in[1];
    const float* Wl     = (const float*)d_in[2];
    const float* Wr     = (const float*)d_in[3];
    const float* att    = (const float*)d_in[4];
    const float* gat_b  = (const float*)d_in[5];
    const float* W_time = (const float*)d_in[6];
    const float* b_time = (const float*)d_in[7];
    const float* W_res  = (const float*)d_in[8];
    const float* b_res  = (const float*)d_in[9];
    const float* ln_g   = (const float*)d_in[10];
    const float* ln_b   = (const float*)d_in[11];
    const float* Wf     = (const float*)d_in[12];
    const float* bf     = (const float*)d_in[13];
    float* out = (float*)d_out;

    char* ws = (char*)d_ws;
    const size_t MB = 1024 * 1024;
    float* hl    = (float*)(ws);                    // 32 MB
    float* hr    = (float*)(ws + 32 * MB);          // 32 MB (becomes X_hat)
    float* rs    = (float*)(ws + 64 * MB);          // 32 MB residual
    int*   ssrc  = (int*)  (ws + 96 * MB);          // 8 MB
    int*   cnt   = (int*)  (ws + 104 * MB);         // 512 KB
    int*   strt  = (int*)  (ws + 104 * MB + 512 * 1024);
    float* wtT   = (float*)(ws + 105 * MB);         // 16 KB
    int*   segs2 = (int*)  (ws + 105 * MB + 32768); // 16 KB [t][8][16]
    int*   cnt2  = (int*)  (ws + 106 * MB);         // 4 MB [t][8][NP]; start2 in-place after scan

    k_front<<<3280, 256, 0, stream>>>(X, Wl, Wr, W_res, b_res, W_time, bf, EI,
                                      hl, hr, rs, wtT, out, cnt2, segs2);
    k_scan <<<NT * 16, 256, 0, stream>>>(cnt2, segs2, cnt, strt);
    k_fill <<<1024, 256, 0, stream>>>(EI, cnt2, ssrc);
    k_gat  <<<(NT * NP) / 4, 256, 0, stream>>>(hl, hr, strt, cnt, ssrc, att, gat_b);
    k_pf   <<<512, 256, 0, stream>>>(hr, wtT, b_time, rs, ln_g, ln_b, Wf, out);
}

// Round 13
// 278.211 us; speedup vs baseline: 1.0290x; 1.0030x over previous
//
#include <hip/hip_runtime.h>
#include <math.h>

#define NP 4096
#define F_IN 64
#define HG 64
#define NC 64
#define NT 32
#define NE 65536
#define HOUT 12
#define LEAKY 0.2f
#define LN_EPS 1e-5f

// ---- DPP reductions ----
template <int CTRL>
__device__ __forceinline__ float dppadd(float v, float x) {   // v + dpp(x); invalid lanes add 0
    int r = __builtin_amdgcn_update_dpp(0, __builtin_bit_cast(int, x), CTRL, 0xF, 0xF, false);
    return v + __builtin_bit_cast(float, r);
}
__device__ __forceinline__ float rowsum16(float v) {   // every lane gets its row-of-16 total
    v = dppadd<0x128>(v, v);   // row_ror:8
    v = dppadd<0x124>(v, v);   // row_ror:4
    v = dppadd<0x122>(v, v);   // row_ror:2
    v = dppadd<0x121>(v, v);   // row_ror:1
    return v;
}
__device__ __forceinline__ float laneXorSum(float v) { // lane-wise cross-row butterfly (16,32)
    v += __shfl_xor(v, 16, 64);
    v += __shfl_xor(v, 32, 64);
    return v;
}
__device__ __forceinline__ int waveSumInt(int v) {
#pragma unroll
    for (int d = 1; d < 64; d <<= 1) v += __shfl_xor(v, d, 64);
    return v;
}

#define FMA4(Acomp, B, r)                                                     \
    acc[r][0] += (Acomp) * (B).x; acc[r][1] += (Acomp) * (B).y;               \
    acc[r][2] += (Acomp) * (B).z; acc[r][3] += (Acomp) * (B).w;

// ============ K_FRONT: one launch, independent roles ============
// blocks [0,1024):     CSR count (t, chunk c of NE/8, range r of 1024 dsts)
// blocks [1024,3072):  hlhr GEMM (2 p per block, 3 passes: Wl, Wr, W_resT)
// blocks [3072,3088):  W_time transpose -> wtT
// blocks [3088,3280):  out init with bias
__global__ __launch_bounds__(256) void k_front(const float* __restrict__ X,
        const float* __restrict__ Wl, const float* __restrict__ Wr,
        const float* __restrict__ W_res, const float* __restrict__ b_res,
        const float* __restrict__ W_time, const float* __restrict__ bf,
        const int* __restrict__ EI,
        float* __restrict__ hl, float* __restrict__ hr, float* __restrict__ rs,
        float* __restrict__ wtT, float* __restrict__ out,
        int* __restrict__ cnt2, int* __restrict__ segsum2) {
    __shared__ float smem[8960];   // 35 KB: xs [0,4608), bk [4608,8960) -> 4 blocks/CU
    int b = blockIdx.x;
    int tid = threadIdx.x;
    if (b < 1024) {
        // ---- count ----
        int* loc = (int*)smem;      // [1024]
        int j = b >> 3;
        int t = (b & 7) + 8 * (j & 3);   // t pinned to XCD
        int cr = j >> 2;
        int c = cr & 7, r = cr >> 3;
        loc[tid] = 0; loc[tid + 256] = 0; loc[tid + 512] = 0; loc[tid + 768] = 0;
        __syncthreads();
        int base = r << 10;
        const int4* dstA = (const int4*)(EI + (size_t)t * 2 * NE + NE) + c * (NE / 32);
        for (int i = tid; i < NE / 32; i += 256) {
            int4 d = dstA[i];
            if ((d.x >> 10) == r) atomicAdd(&loc[d.x - base], 1);
            if ((d.y >> 10) == r) atomicAdd(&loc[d.y - base], 1);
            if ((d.z >> 10) == r) atomicAdd(&loc[d.z - base], 1);
            if ((d.w >> 10) == r) atomicAdd(&loc[d.w - base], 1);
        }
        __syncthreads();
        int o = (t * 8 + c) * NP + base + tid;
        cnt2[o] = loc[tid];
        cnt2[o + 256] = loc[tid + 256];
        cnt2[o + 512] = loc[tid + 512];
        cnt2[o + 768] = loc[tid + 768];
        int wv = tid >> 6, lane = tid & 63;
        int s = loc[wv * 256 + lane] + loc[wv * 256 + lane + 64]
              + loc[wv * 256 + lane + 128] + loc[wv * 256 + lane + 192];
        s = waveSumInt(s);
        if (lane == 0) segsum2[(t * 8 + c) * 16 + r * 4 + wv] = s;
    } else if (b < 3072) {
        // ---- hlhr 3-pass: xs[2][64][36], bk[64][68] ----
        float (*xs)[F_IN][36] = (float (*)[F_IN][36])smem;
        float (*bk)[68] = (float (*)[68])(smem + 4608);
        int p0 = (b - 1024) * 2;
        const float4* Xp = (const float4*)(X + (size_t)p0 * F_IN * NT);
        for (int i4 = tid; i4 < 1024; i4 += 256) {
            int pp = i4 >> 9, f = (i4 >> 3) & 63, t0 = (i4 & 7) * 4;
            *(float4*)&xs[pp][f][t0] = Xp[i4];
        }
        // thread layout (all passes): ng = tid&15 (4 cols), pp = (tid>>4)&1, tg = tid>>5 (4 t)
        int ng = tid & 15, pp = (tid >> 4) & 1, tg = tid >> 5;
        int n0 = ng * 4, t0 = tg * 4;
        // ---- pass 1: Wl -> hl ----
        {
            const float4* B4 = (const float4*)Wl;
            for (int i4 = tid; i4 < 1024; i4 += 256)
                *(float4*)&bk[i4 >> 4][(i4 & 15) * 4] = B4[i4];
            __syncthreads();
            float acc[4][4];
#pragma unroll
            for (int i = 0; i < 4; ++i)
#pragma unroll
                for (int j2 = 0; j2 < 4; ++j2) acc[i][j2] = 0.f;
#pragma unroll 8
            for (int f = 0; f < F_IN; ++f) {
                float4 B = *(const float4*)&bk[f][n0];
                float4 A = *(const float4*)&xs[pp][f][t0];
                FMA4(A.x, B, 0) FMA4(A.y, B, 1) FMA4(A.z, B, 2) FMA4(A.w, B, 3)
            }
#pragma unroll
            for (int i = 0; i < 4; ++i) {
                float4 v;
                v.x = acc[i][0]; v.y = acc[i][1]; v.z = acc[i][2]; v.w = acc[i][3];
                *(float4*)&hl[((size_t)(t0 + i) * NP + p0 + pp) * HG + n0] = v;
            }
            __syncthreads();
        }
        // ---- pass 2: Wr -> hr ----
        {
            const float4* B4 = (const float4*)Wr;
            for (int i4 = tid; i4 < 1024; i4 += 256)
                *(float4*)&bk[i4 >> 4][(i4 & 15) * 4] = B4[i4];
            __syncthreads();
            float acc[4][4];
#pragma unroll
            for (int i = 0; i < 4; ++i)
#pragma unroll
                for (int j2 = 0; j2 < 4; ++j2) acc[i][j2] = 0.f;
#pragma unroll 8
            for (int f = 0; f < F_IN; ++f) {
                float4 B = *(const float4*)&bk[f][n0];
                float4 A = *(const float4*)&xs[pp][f][t0];
                FMA4(A.x, B, 0) FMA4(A.y, B, 1) FMA4(A.z, B, 2) FMA4(A.w, B, 3)
            }
#pragma unroll
            for (int i = 0; i < 4; ++i) {
                float4 v;
                v.x = acc[i][0]; v.y = acc[i][1]; v.z = acc[i][2]; v.w = acc[i][3];
                *(float4*)&hr[((size_t)(t0 + i) * NP + p0 + pp) * HG + n0] = v;
            }
            __syncthreads();
        }
        // ---- pass 3: W_res^T -> rs ----
        {
            for (int i = tid; i < F_IN * NC; i += 256) {
                int c = i >> 6, f = i & 63;       // W_res[c][f] coalesced read
                bk[f][c] = W_res[i];              // transposed write (conflicted, once)
            }
            __syncthreads();
            float4 br4 = *(const float4*)&b_res[n0];
            float acc[4][4];
#pragma unroll
            for (int i = 0; i < 4; ++i) {
                acc[i][0] = br4.x; acc[i][1] = br4.y; acc[i][2] = br4.z; acc[i][3] = br4.w;
            }
#pragma unroll 8
            for (int f = 0; f < F_IN; ++f) {
                float4 B = *(const float4*)&bk[f][n0];
                float4 A = *(const float4*)&xs[pp][f][t0];
                FMA4(A.x, B, 0) FMA4(A.y, B, 1) FMA4(A.z, B, 2) FMA4(A.w, B, 3)
            }
#pragma unroll
            for (int i = 0; i < 4; ++i) {
                float4 v;
                v.x = acc[i][0]; v.y = acc[i][1]; v.z = acc[i][2]; v.w = acc[i][3];
                *(float4*)&rs[((size_t)(t0 + i) * NP + p0 + pp) * NC + n0] = v;
            }
        }
    } else if (b < 3088) {
        int i = (b - 3072) * 256 + tid;
        wtT[i] = W_time[(i & 63) * 64 + (i >> 6)];
    } else {
        int i = (b - 3088) * 256 + tid;       // 0 .. NP*HOUT-1
        out[i] = bf[i % HOUT];
    }
}

// ---- K2b: scan; block = (t, 256-dst segment); start2 written in-place over cnt2 ----
__global__ __launch_bounds__(256) void k_scan(int* __restrict__ cnt2,
        const int* __restrict__ segsum2, int* __restrict__ cnt,
        int* __restrict__ start) {
    __shared__ int sc[256];
    __shared__ int preS;
    int b = blockIdx.x;
    int t = b >> 4, seg = b & 15;
    int tid = threadIdx.x;
    if (tid < 64) {
        int s = tid & 15, cp = tid >> 4;
        int v = 0;
        if (s < seg) {
            v = segsum2[(t * 8 + cp * 2 + 0) * 16 + s]
              + segsum2[(t * 8 + cp * 2 + 1) * 16 + s];
        }
        v = waveSumInt(v);
        if (tid == 0) preS = v;
    }
    int d = seg * 256 + tid;
    int q[8];
    int deg = 0;
#pragma unroll
    for (int c = 0; c < 8; ++c) {
        q[c] = cnt2[(t * 8 + c) * NP + d];
        deg += q[c];
    }
    sc[tid] = deg;
    __syncthreads();
    int pre = preS;
    for (int dd = 1; dd < 256; dd <<= 1) {
        int v = (tid >= dd) ? sc[tid - dd] : 0;
        __syncthreads();
        sc[tid] += v;
        __syncthreads();
    }
    int exc = sc[tid] - deg;
    int st = t * NE + pre + exc;
    cnt[t * NP + d] = deg;
    start[t * NP + d] = st;
#pragma unroll
    for (int c = 0; c < 8; ++c) {
        int qq = q[c];
        cnt2[(t * 8 + c) * NP + d] = st;      // becomes start2
        st += qq;
    }
}

// ---- K2c: fill; block = (t, chunk c of NE/8, range r); LDS cursors ----
__global__ __launch_bounds__(256) void k_fill(const int* __restrict__ EI,
        const int* __restrict__ start2, int* __restrict__ ssrc) {
    __shared__ int curs_l[1024];
    int b = blockIdx.x;
    int j = b >> 3;
    int t = (b & 7) + 8 * (j & 3);
    int cr = j >> 2;
    int c = cr & 7, r = cr >> 3;
    int tid = threadIdx.x;
    int base = r << 10;
    int o = (t * 8 + c) * NP + base + tid;
    curs_l[tid] = start2[o];
    curs_l[tid + 256] = start2[o + 256];
    curs_l[tid + 512] = start2[o + 512];
    curs_l[tid + 768] = start2[o + 768];
    __syncthreads();
    const int4* srcA = (const int4*)(EI + (size_t)t * 2 * NE) + c * (NE / 32);
    const int4* dstA = (const int4*)(EI + (size_t)t * 2 * NE + NE) + c * (NE / 32);
    for (int i = tid; i < NE / 32; i += 256) {
        int4 s = srcA[i];
        int4 d = dstA[i];
        if ((d.x >> 10) == r) { int sl = atomicAdd(&curs_l[d.x - base], 1); ssrc[sl] = s.x; }
        if ((d.y >> 10) == r) { int sl = atomicAdd(&curs_l[d.y - base], 1); ssrc[sl] = s.y; }
        if ((d.z >> 10) == r) { int sl = atomicAdd(&curs_l[d.z - base], 1); ssrc[sl] = s.z; }
        if ((d.w >> 10) == r) { int sl = atomicAdd(&curs_l[d.w - base], 1); ssrc[sl] = s.w; }
    }
}

// ---- K3: GATv2; wave per dst; 8 edges/iter (2 independent 4-edge chains) ----
__global__ __launch_bounds__(256) void k_gat(const float* __restrict__ hl,
        float* __restrict__ hr,
        const int* __restrict__ start, const int* __restrict__ cnt,
        const int* __restrict__ ssrc,
        const float* __restrict__ att, const float* __restrict__ gat_b) {
    __shared__ int sidx[4][64];
    int b = blockIdx.x;              // 32768 blocks
    int k = b >> 3;                  // 0..4095
    int t = (b & 7) + 8 * (k >> 10); // one t per XCD at a time
    int ws = threadIdx.x >> 6;
    int i = (k & 1023) * 4 + ws;
    int lane = threadIdx.x & 63;
    int row = lane >> 4;
    int c0 = (lane & 15) * 4;
    size_t nbase = ((size_t)t * NP + i) * HG;
    const float* hlt = hl + (size_t)t * NP * HG;
    float4 r4 = *(const float4*)&hr[nbase + c0];
    float4 at4 = *(const float4*)&att[c0];
    int s0 = start[t * NP + i];
    int deg = cnt[t * NP + i];
    float l = 0.f;
    float4 acc = {0.f, 0.f, 0.f, 0.f};
    for (int base = 0; base < deg; base += 64) {
        int chunk = deg - base;
        chunk = (chunk < 64) ? chunk : 64;
        int stage = (lane < chunk) ? lane : 0;
        sidx[ws][lane] = ssrc[s0 + base + stage];
        int nfull = chunk & ~7;
        int j = 0;
        for (; j < nfull; j += 8) {
            int src0 = sidx[ws][j + row];
            int src1 = sidx[ws][j + 4 + row];
            float4 h0 = *(const float4*)&hlt[((size_t)src0 << 6) + c0];
            float4 h1 = *(const float4*)&hlt[((size_t)src1 << 6) + c0];
            float4 z0, z1;
            z0.x = h0.x + r4.x; z0.y = h0.y + r4.y; z0.z = h0.z + r4.z; z0.w = h0.w + r4.w;
            z1.x = h1.x + r4.x; z1.y = h1.y + r4.y; z1.z = h1.z + r4.z; z1.w = h1.w + r4.w;
            z0.x = fmaxf(z0.x, LEAKY * z0.x); z0.y = fmaxf(z0.y, LEAKY * z0.y);
            z0.z = fmaxf(z0.z, LEAKY * z0.z); z0.w = fmaxf(z0.w, LEAKY * z0.w);
            z1.x = fmaxf(z1.x, LEAKY * z1.x); z1.y = fmaxf(z1.y, LEAKY * z1.y);
            z1.z = fmaxf(z1.z, LEAKY * z1.z); z1.w = fmaxf(z1.w, LEAKY * z1.w);
            float e0 = rowsum16(z0.x * at4.x + z0.y * at4.y + z0.z * at4.z + z0.w * at4.w);
            float e1 = rowsum16(z1.x * at4.x + z1.y * at4.y + z1.z * at4.z + z1.w * at4.w);
            float w0 = __expf(e0);
            float w1 = __expf(e1);
            l += w0 + w1;
            acc.x += w0 * h0.x + w1 * h1.x;
            acc.y += w0 * h0.y + w1 * h1.y;
            acc.z += w0 * h0.z + w1 * h1.z;
            acc.w += w0 * h0.w + w1 * h1.w;
        }
        for (; j < chunk; j += 4) {
            int jj = j + row;
            int src = sidx[ws][(jj < chunk) ? jj : 0];
            float4 ha = *(const float4*)&hlt[((size_t)src << 6) + c0];
            float4 za;
            za.x = ha.x + r4.x; za.y = ha.y + r4.y; za.z = ha.z + r4.z; za.w = ha.w + r4.w;
            za.x = fmaxf(za.x, LEAKY * za.x);
            za.y = fmaxf(za.y, LEAKY * za.y);
            za.z = fmaxf(za.z, LEAKY * za.z);
            za.w = fmaxf(za.w, LEAKY * za.w);
            float ep = za.x * at4.x + za.y * at4.y + za.z * at4.z + za.w * at4.w;
            float e = rowsum16(ep);
            float w = __expf(e);
            w = (jj < chunk) ? w : 0.f;
            l += w;
            acc.x += w * ha.x; acc.y += w * ha.y; acc.z += w * ha.z; acc.w += w * ha.w;
        }
    }
    float lt = laneXorSum(l);
    acc.x = laneXorSum(acc.x);
    acc.y = laneXorSum(acc.y);
    acc.z = laneXorSum(acc.z);
    acc.w = laneXorSum(acc.w);
    if (row == 0) {
        float inv = (deg > 0) ? (1.0f / lt) : 0.f;
        float4 gb = *(const float4*)&gat_b[c0];
        float4 o;
        o.x = fmaxf(acc.x * inv + gb.x, 0.f);
        o.y = fmaxf(acc.y * inv + gb.y, 0.f);
        o.z = fmaxf(acc.z * inv + gb.z, 0.f);
        o.w = fmaxf(acc.w * inv + gb.w, 0.f);
        *(float4*)&hr[nbase + c0] = o;
    }
}

// ---- K4 (fused post+final): per (64-p tile, 4 stride-8 t's) ----
__global__ __launch_bounds__(256) void k_pf(const float* __restrict__ Xhat,
        const float* __restrict__ wtT, const float* __restrict__ b_time,
        const float* __restrict__ rs, const float* __restrict__ ln_g,
        const float* __restrict__ ln_b, const float* __restrict__ Wf,
        float* __restrict__ out) {
    __shared__ float in_t[64][68];
    __shared__ float bk[64][68];
    int bx = blockIdx.x;             // 512 = 64 ptiles x 8 tchunks
    int tc = bx & 7;
    int p0 = (bx >> 3) * 64;
    int tid = threadIdx.x;
    const float4* wsrc = (const float4*)wtT;
    for (int i4 = tid; i4 < 1024; i4 += 256) {
        int h = i4 >> 4, c4 = (i4 & 15) * 4;
        *(float4*)&bk[h][c4] = wsrc[i4];
    }
    int cg = tid & 15, pg = tid >> 4;
    int c0 = cg * 4, pl = pg * 4;
    float4 bt4 = *(const float4*)&b_time[c0];
    float4 lg = *(const float4*)&ln_g[c0];
    float4 lb = *(const float4*)&ln_b[c0];
    float ot[4][HOUT];
#pragma unroll
    for (int i = 0; i < 4; ++i)
#pragma unroll
        for (int o = 0; o < HOUT; ++o) ot[i][o] = 0.f;
    for (int ti = 0; ti < 4; ++ti) {
        int t = tc + ti * 8;
        __syncthreads();
        const float4* src = (const float4*)(Xhat + ((size_t)t * NP + p0) * HG);
        for (int i4 = tid; i4 < 1024; i4 += 256) {
            int pp = i4 >> 4, c4 = (i4 & 15) * 4;
            *(float4*)&in_t[pp][c4] = src[i4];
        }
        __syncthreads();
        float acc[4][4];
#pragma unroll
        for (int i = 0; i < 4; ++i) {
            acc[i][0] = bt4.x; acc[i][1] = bt4.y; acc[i][2] = bt4.z; acc[i][3] = bt4.w;
        }
#pragma unroll
        for (int k4 = 0; k4 < 16; ++k4) {
            float4 A0 = *(const float4*)&in_t[pl + 0][k4 * 4];
            float4 A1 = *(const float4*)&in_t[pl + 1][k4 * 4];
            float4 A2 = *(const float4*)&in_t[pl + 2][k4 * 4];
            float4 A3 = *(const float4*)&in_t[pl + 3][k4 * 4];
            float4 B0 = *(const float4*)&bk[k4 * 4 + 0][c0];
            FMA4(A0.x, B0, 0) FMA4(A1.x, B0, 1) FMA4(A2.x, B0, 2) FMA4(A3.x, B0, 3)
            float4 B1 = *(const float4*)&bk[k4 * 4 + 1][c0];
            FMA4(A0.y, B1, 0) FMA4(A1.y, B1, 1) FMA4(A2.y, B1, 2) FMA4(A3.y, B1, 3)
            float4 B2 = *(const float4*)&bk[k4 * 4 + 2][c0];
            FMA4(A0.z, B2, 0) FMA4(A1.z, B2, 1) FMA4(A2.z, B2, 2) FMA4(A3.z, B2, 3)
            float4 B3 = *(const float4*)&bk[k4 * 4 + 3][c0];
            FMA4(A0.w, B3, 0) FMA4(A1.w, B3, 1) FMA4(A2.w, B3, 2) FMA4(A3.w, B3, 3)
        }
        float4 ynv[4];
#pragma unroll
        for (int i = 0; i < 4; ++i) {
            size_t prow = (size_t)t * NP + p0 + pl + i;
            float4 r4 = *(const float4*)&rs[prow * NC + c0];
            float y0 = fmaxf(acc[i][0] + r4.x, 0.f), y1 = fmaxf(acc[i][1] + r4.y, 0.f);
            float y2 = fmaxf(acc[i][2] + r4.z, 0.f), y3 = fmaxf(acc[i][3] + r4.w, 0.f);
            float s = rowsum16(y0 + y1 + y2 + y3);
            float ss = rowsum16(y0 * y0 + y1 * y1 + y2 * y2 + y3 * y3);
            float mu = s * (1.f / 64.f);
            float var = ss * (1.f / 64.f) - mu * mu;
            float rsd = rsqrtf(var + LN_EPS);
            ynv[i].x = (y0 - mu) * rsd * lg.x + lb.x;
            ynv[i].y = (y1 - mu) * rsd * lg.y + lb.y;
            ynv[i].z = (y2 - mu) * rsd * lg.z + lb.z;
            ynv[i].w = (y3 - mu) * rsd * lg.w + lb.w;
        }
#pragma unroll
        for (int o = 0; o < HOUT; ++o) {
            float4 w4 = *(const float4*)&Wf[(size_t)o * NT * NC + t * NC + c0];
#pragma unroll
            for (int i = 0; i < 4; ++i)
                ot[i][o] += ynv[i].x * w4.x + ynv[i].y * w4.y
                          + ynv[i].z * w4.z + ynv[i].w * w4.w;
        }
    }
#pragma unroll
    for (int i = 0; i < 4; ++i)
#pragma unroll
        for (int o = 0; o < HOUT; ++o) ot[i][o] = rowsum16(ot[i][o]);
    if (cg == 0) {
#pragma unroll
        for (int i = 0; i < 4; ++i) {
            int p = p0 + pl + i;
#pragma unroll
            for (int o = 0; o < HOUT; ++o)
                atomicAdd(&out[p * HOUT + o], ot[i][o]);
        }
    }
}

extern "C" void kernel_launch(void* const* d_in, const int* in_sizes, int n_in,
                              void* d_out, int out_size, void* d_ws, size_t ws_size,
                              hipStream_t stream) {
    const float* X      = (const float*)d_in[0];
    const int*   EI     = (const int*)d_in[1];
    const float* Wl     = (const float*)d_in[2];
    const float* Wr     = (const float*)d_in[3];
    const float* att    = (const float*)d_in[4];
    const float* gat_b  = (const float*)d_in[5];
    const float* W_time = (const float*)d_in[6];
    const float* b_time = (const float*)d_in[7];
    const float* W_res  = (const float*)d_in[8];
    const float* b_res  = (const float*)d_in[9];
    const float* ln_g   = (const float*)d_in[10];
    const float* ln_b   = (const float*)d_in[11];
    const float* Wf     = (const float*)d_in[12];
    const float* bf     = (const float*)d_in[13];
    float* out = (float*)d_out;

    char* ws = (char*)d_ws;
    const size_t MB = 1024 * 1024;
    float* hl    = (float*)(ws);                    // 32 MB
    float* hr    = (float*)(ws + 32 * MB);          // 32 MB (becomes X_hat)
    float* rs    = (float*)(ws + 64 * MB);          // 32 MB residual
    int*   ssrc  = (int*)  (ws + 96 * MB);          // 8 MB
    int*   cnt   = (int*)  (ws + 104 * MB);         // 512 KB
    int*   strt  = (int*)  (ws + 104 * MB + 512 * 1024);
    float* wtT   = (float*)(ws + 105 * MB);         // 16 KB
    int*   segs2 = (int*)  (ws + 105 * MB + 32768); // 16 KB [t][8][16]
    int*   cnt2  = (int*)  (ws + 106 * MB);         // 4 MB [t][8][NP]; start2 in-place after scan

    k_front<<<3280, 256, 0, stream>>>(X, Wl, Wr, W_res, b_res, W_time, bf, EI,
                                      hl, hr, rs, wtT, out, cnt2, segs2);
    k_scan <<<NT * 16, 256, 0, stream>>>(cnt2, segs2, cnt, strt);
    k_fill <<<1024, 256, 0, stream>>>(EI, cnt2, ssrc);
    k_gat  <<<(NT * NP) / 4, 256, 0, stream>>>(hl, hr, strt, cnt, ssrc, att, gat_b);
    k_pf   <<<512, 256, 0, stream>>>(hr, wtT, b_time, rs, ln_g, ln_b, Wf, out);
}